// Round 1
// 417.627 us; speedup vs baseline: 1.1603x; 1.1603x over previous
//
#include <hip/hip_runtime.h>

// ---------------------------------------------------------------------------
// NASNet controller: 8 sequential LSTM steps (B=4096, H=512) + 16 decisions.
//  - Steps 1-4 run on class representatives (1/8/64/512 rows): rows only
//    differ through sampled op tokens (8^s classes).
//  - Steps 5-7: full GEMMs on the MFMA pipe via split-bf16 (hi+lo) emulation:
//    A*B ~= Ahi*Bhi + Ahi*Blo + Alo*Bhi  == one bf16 GEMM with K=1536.
//  - R4: XOR-swizzled LDS layout (16B-chunk c of row r stored at c^(r&7)).
//  - R5: double-buffered LDS prefetch (stage tile t+1 before computing tile t,
//    ONE barrier per K-iter -> load latency hides under MFMA) + XCD-aware
//    superblock blockIdx swizzle (each XCD gets an 8x8 tile region so its
//    ~5MB working set approx fits the per-XCD 4MB L2).
// ---------------------------------------------------------------------------

constexpr int Bsz = 4096;
constexpr int Hsz = 512;
constexpr int G4H = 2048;

typedef unsigned short ushort_t;
using short8 = __attribute__((ext_vector_type(8))) short;
using f32x4 = __attribute__((ext_vector_type(4))) float;

__device__ __forceinline__ ushort_t f2bf_hi(float f) {
  unsigned u = __float_as_uint(f);
  u += 0x7FFF + ((u >> 16) & 1);  // RNE
  return (ushort_t)(u >> 16);
}
__device__ __forceinline__ float bf2f(ushort_t h) {
  return __uint_as_float((unsigned)h << 16);
}

__device__ __forceinline__ void glds16(const void* gsrc, void* ldst) {
  __builtin_amdgcn_global_load_lds(
      (const __attribute__((address_space(1))) void*)gsrc,
      (__attribute__((address_space(3))) void*)ldst, 16, 0, 0);
}

// ---------------- E = emb @ w_ih^T + b_ih + b_hh (std + ct-permuted) -------
__global__ __launch_bounds__(256) void precompute_E(
    const float* __restrict__ emb, const float* __restrict__ w_ih,
    const float* __restrict__ b_ih, const float* __restrict__ b_hh,
    float* __restrict__ E, float* __restrict__ Eperm) {
  int idx = blockIdx.x * 256 + threadIdx.x;  // t*2048 + col
  int t = idx >> 11;
  int col = idx & 2047;
  const float* er = emb + (size_t)t * Hsz;
  const float* wr = w_ih + (size_t)col * Hsz;
  float acc = 0.0f;
  for (int k = 0; k < Hsz; k += 4) {
    float4 e = *(const float4*)(er + k);
    float4 w = *(const float4*)(wr + k);
    acc += e.x * w.x + e.y * w.y + e.z * w.z + e.w * w.w;
  }
  float v = acc + b_ih[col] + b_hh[col];
  E[idx] = v;
  int g = col >> 9, j = col & 511;
  Eperm[(size_t)t * G4H + (j << 2) + g] = v;
}

// ---------------- W_cat: [2048 ct rows][1536] bf16 = [hi | lo | hi] --------
__global__ __launch_bounds__(256) void build_wcat(
    const float* __restrict__ w_hh, ushort_t* __restrict__ Wcat) {
  int ct = blockIdx.y;
  int k = blockIdx.x * 256 + threadIdx.x;  // 0..1535
  int j = ct >> 2, g = ct & 3;
  const float* srcrow = w_hh + (size_t)(g * 512 + j) * Hsz;
  ushort_t out;
  if (k < 512) {
    out = f2bf_hi(srcrow[k]);
  } else if (k < 1024) {
    float x = srcrow[k - 512];
    ushort_t hi = f2bf_hi(x);
    out = f2bf_hi(x - bf2f(hi));
  } else {
    out = f2bf_hi(srcrow[k - 1024]);
  }
  Wcat[(size_t)ct * 1536 + k] = out;
}

// ---------------- class GEMM: G[q][col] = dot(h[q], w[col]) ----------------
__global__ __launch_bounds__(256) void class_gemm(
    const float* __restrict__ h, const float* __restrict__ w,
    float* __restrict__ G, int nq) {
  const int wid = (blockIdx.x << 2) + (threadIdx.x >> 6);
  const int lane = threadIdx.x & 63;
  const int q = wid >> 11;
  const int col = wid & 2047;
  if (q >= nq) return;
  const float* hr = h + (size_t)q * Hsz + (lane << 3);
  const float* wr = w + (size_t)col * Hsz + (lane << 3);
  float4 a0 = *(const float4*)(hr);
  float4 a1 = *(const float4*)(hr + 4);
  float4 b0 = *(const float4*)(wr);
  float4 b1 = *(const float4*)(wr + 4);
  float v = a0.x * b0.x + a0.y * b0.y + a0.z * b0.z + a0.w * b0.w +
            a1.x * b1.x + a1.y * b1.y + a1.z * b1.z + a1.w * b1.w;
#pragma unroll
  for (int off = 32; off > 0; off >>= 1) v += __shfl_xor(v, off, 64);
  if (lane == 0) G[(size_t)q * G4H + col] = v;
}

// ---------------- 64x64-tiled fp32 GEMM (step 4, M=512) --------------------
__global__ __launch_bounds__(256) void gemm64(
    const float* __restrict__ A, const float* __restrict__ Bw,
    float* __restrict__ G) {
  constexpr int LDA = 68;
  __shared__ float As[16 * LDA];
  __shared__ float Bs[16 * LDA];
  const int tid = threadIdx.x;
  const int bx = blockIdx.x & 31;
  const int by = blockIdx.x >> 5;
  const int r0 = by * 64, c0 = bx * 64;
  const int tx = tid & 15, ty = tid >> 4;
  const int lr = tid >> 2;
  const int lk = (tid & 3) << 2;
  const float* Ar = A + (size_t)(r0 + lr) * Hsz;
  const float* Br = Bw + (size_t)(c0 + lr) * Hsz;
  float acc[4][4];
#pragma unroll
  for (int i = 0; i < 4; ++i)
#pragma unroll
    for (int j = 0; j < 4; ++j) acc[i][j] = 0.0f;

  for (int k0 = 0; k0 < Hsz; k0 += 16) {
    float4 a = *(const float4*)(Ar + k0 + lk);
    float4 b = *(const float4*)(Br + k0 + lk);
    __syncthreads();
    As[(lk + 0) * LDA + lr] = a.x;
    As[(lk + 1) * LDA + lr] = a.y;
    As[(lk + 2) * LDA + lr] = a.z;
    As[(lk + 3) * LDA + lr] = a.w;
    Bs[(lk + 0) * LDA + lr] = b.x;
    Bs[(lk + 1) * LDA + lr] = b.y;
    Bs[(lk + 2) * LDA + lr] = b.z;
    Bs[(lk + 3) * LDA + lr] = b.w;
    __syncthreads();
#pragma unroll
    for (int kk = 0; kk < 16; ++kk) {
      float4 av = *(const float4*)&As[kk * LDA + (ty << 2)];
      float4 bv = *(const float4*)&Bs[kk * LDA + (tx << 2)];
      float avs[4] = {av.x, av.y, av.z, av.w};
      float bvs[4] = {bv.x, bv.y, bv.z, bv.w};
#pragma unroll
      for (int i = 0; i < 4; ++i)
#pragma unroll
        for (int j = 0; j < 4; ++j) acc[i][j] = fmaf(avs[i], bvs[j], acc[i][j]);
    }
  }
#pragma unroll
  for (int i = 0; i < 4; ++i)
#pragma unroll
    for (int j = 0; j < 4; ++j)
      G[(size_t)(r0 + (ty << 2) + i) * G4H + c0 + (tx << 2) + j] = acc[i][j];
}

// ---------------- class pointwise ------------------------------------------
__global__ __launch_bounds__(256) void step_pw(
    const float* __restrict__ G, const float* __restrict__ E,
    const float* __restrict__ c_prev, float* __restrict__ h_out,
    float* __restrict__ c_out, int nq) {
  int idx = blockIdx.x * 256 + threadIdx.x;
  if (idx >= nq * Hsz) return;
  int q = idx >> 9, j = idx & 511;
  int gq = q >> 3, er = q & 7;
  const float* Eg = E + (size_t)er * G4H;
  float iv = Eg[j], fv = Eg[512 + j], gv = Eg[1024 + j], ov = Eg[1536 + j];
  if (G) {
    const float* Gg = G + (size_t)gq * G4H;
    iv += Gg[j]; fv += Gg[512 + j]; gv += Gg[1024 + j]; ov += Gg[1536 + j];
  }
  float cp = c_prev ? c_prev[(size_t)gq * Hsz + j] : 0.0f;
  float ig = 1.0f / (1.0f + expf(-iv));
  float fg = 1.0f / (1.0f + expf(-fv));
  float gg = tanhf(gv);
  float og = 1.0f / (1.0f + expf(-ov));
  float cn = fg * cp + ig * gg;
  c_out[idx] = cn;
  h_out[idx] = og * tanhf(cn);
}

// ---------------- step-4 expansion: classes (512) -> rows (4096) -----------
__global__ __launch_bounds__(256) void expand_pw(
    const float* __restrict__ G, const float* __restrict__ E,
    const float* __restrict__ c4, const int* __restrict__ cls3,
    const int* __restrict__ act3, float* __restrict__ h_out,
    float* __restrict__ c_out, ushort_t* __restrict__ Acat) {
  int idx = blockIdx.x * 256 + threadIdx.x;
  int r = idx >> 9, j = idx & 511;
  int q = cls3[r], er = act3[r];
  const float* Eg = E + (size_t)er * G4H;
  const float* Gg = G + (size_t)q * G4H;
  float iv = Gg[j] + Eg[j];
  float fv = Gg[512 + j] + Eg[512 + j];
  float gv = Gg[1024 + j] + Eg[1024 + j];
  float ov = Gg[1536 + j] + Eg[1536 + j];
  float cp = c4[(size_t)q * Hsz + j];
  float ig = 1.0f / (1.0f + expf(-iv));
  float fg = 1.0f / (1.0f + expf(-fv));
  float gg = tanhf(gv);
  float og = 1.0f / (1.0f + expf(-ov));
  float cn = fg * cp + ig * gg;
  float hn = og * tanhf(cn);
  c_out[idx] = cn;
  h_out[idx] = hn;
  ushort_t hi = f2bf_hi(hn);
  Acat[(size_t)r * 1024 + j] = hi;
  Acat[(size_t)r * 1024 + 512 + j] = f2bf_hi(hn - bf2f(hi));
}

// ---------------- split-bf16 MFMA GEMM + fused LSTM pointwise --------------
// C[4096 x 2048ct] = Acat(logical [hi|hi|lo]) @ Wcat^T (rows = ct, [hi|lo|hi])
// tile 128x128, BK=64, 4 waves x (4x4 16x16x32 tiles). XOR-swizzled LDS.
// R5: double-buffered prefetch (1 barrier per K-iter), XCD superblock swizzle.
__global__ __launch_bounds__(256) void gemm_bf16_lstm(
    const ushort_t* __restrict__ Acat, const ushort_t* __restrict__ Wcat,
    const float* __restrict__ Eperm, const int* __restrict__ act,
    float* __restrict__ cF, float* __restrict__ h_out,
    ushort_t* __restrict__ Aout) {
  __shared__ union {
    struct { ushort_t A[128 * 64]; ushort_t B[128 * 64]; } s[2];  // 64 KB
    float C[64 * 132];                                            // 33.8 KB
  } sm;

  const int tid = threadIdx.x;
  const int wave = tid >> 6, lane = tid & 63;
  // XCD-aware superblock swizzle: blockIdx%8 round-robins across the 8 XCDs;
  // give each XCD one 8x8 tile region (8 A-panels = 2MB + 8 B-panels = 3MB,
  // ~fits the per-XCD 4MB L2). Bijective: grid 512 = 8 XCD x 64 tiles.
  const int xcd = blockIdx.x & 7;
  const int i64 = blockIdx.x >> 3;                  // 0..63 within XCD
  const int by = ((xcd >> 1) << 3) + (i64 >> 3);    // 32 row tiles (4 sb rows)
  const int bx = ((xcd & 1) << 3) + (i64 & 7);      // 16 col tiles (2 sb cols)
  const int r0 = by * 128, c0 = bx * 128;
  const int wr = (wave >> 1) * 64, wc = (wave & 1) * 64;
  const int mrow = lane & 15, quad = lane >> 4;

  // staging: lane l writes LDS chunk l of its 1KB region (8 rows x 8 chunks);
  // source chunk is XOR-swizzled so physical chunk pc of row lr holds logical
  // chunk pc^lr.
  const int slr = lane >> 3;                    // row-in-region 0..7
  const int ssw = ((lane & 7) ^ slr) << 3;      // swizzled source chunk offset

  f32x4 acc[4][4];
#pragma unroll
  for (int i = 0; i < 4; ++i)
#pragma unroll
    for (int jt = 0; jt < 4; ++jt) acc[i][jt] = (f32x4){0.f, 0.f, 0.f, 0.f};

  auto stage = [&](int buf, int k0) {
    const int ak = (k0 < 512) ? k0 : k0 - 512;  // A dup-block remap
#pragma unroll
    for (int q = 0; q < 8; ++q) {
      const int g = (q << 2) + wave;
      if (g < 16) {
        const int row = r0 + g * 8 + slr;
        glds16(Acat + (size_t)row * 1024 + ak + ssw,
               (char*)sm.s[buf].A + g * 1024);
      } else {
        const int row = c0 + (g - 16) * 8 + slr;
        glds16(Wcat + (size_t)row * 1536 + k0 + ssw,
               (char*)sm.s[buf].B + (g - 16) * 1024);
      }
    }
  };

  // prologue: stage tile 0, drain, barrier
  stage(0, 0);
  __syncthreads();

  int cur = 0;
  for (int it = 0; it < 24; ++it) {
    // issue next tile's loads BEFORE computing current tile; the single
    // __syncthreads() at loop end drains vmcnt(0) AFTER the MFMA cluster,
    // so the load latency hides under compute (T3-minimum 2-phase).
    if (it < 23) stage(cur ^ 1, (it + 1) << 6);
    const ushort_t* As = sm.s[cur].A;
    const ushort_t* Bs = sm.s[cur].B;
#pragma unroll
    for (int kk = 0; kk < 2; ++kk) {
      const int swr = ((kk * 4 + quad) ^ (mrow & 7)) << 3;  // swizzled chunk
      short8 a[4], b[4];
#pragma unroll
      for (int i = 0; i < 4; ++i)
        a[i] = *(const short8*)&As[(wr + i * 16 + mrow) * 64 + swr];
#pragma unroll
      for (int jt = 0; jt < 4; ++jt)
        b[jt] = *(const short8*)&Bs[(wc + jt * 16 + mrow) * 64 + swr];
#pragma unroll
      for (int i = 0; i < 4; ++i)
#pragma unroll
        for (int jt = 0; jt < 4; ++jt)
          acc[i][jt] = __builtin_amdgcn_mfma_f32_16x16x32_bf16(
              a[i], b[jt], acc[i][jt], 0, 0, 0);
    }
    __syncthreads();  // drains this iter's prefetch + protects buf reuse
    cur ^= 1;
  }

  // ---- epilogue: two 64-row phases through LDS, fused LSTM pointwise ----
  const int jj = tid & 31;         // j-local 0..31
  const int rbase = tid >> 5;      // 0..7
#pragma unroll
  for (int p = 0; p < 2; ++p) {
    __syncthreads();  // phase 0: K-loop reads done; phase 1: prev consume done
    if ((wr >> 6) == p) {
#pragma unroll
      for (int i = 0; i < 4; ++i)
#pragma unroll
        for (int jt = 0; jt < 4; ++jt)
#pragma unroll
          for (int rg = 0; rg < 4; ++rg)
            sm.C[(i * 16 + quad * 4 + rg) * 132 + wc + jt * 16 + mrow] =
                acc[i][jt][rg];
    }
    __syncthreads();
#pragma unroll
    for (int rp = 0; rp < 8; ++rp) {
      const int rl = rbase * 8 + rp;           // 0..63
      const int grow = r0 + p * 64 + rl;
      float4 g4 = *(float4*)&sm.C[rl * 132 + jj * 4];
      const int a = act[grow];
      const int jglob = (c0 >> 2) + jj;        // 0..511
      float4 e4 = *(const float4*)&Eperm[(size_t)a * G4H + c0 + jj * 4];
      float iv = g4.x + e4.x, fv = g4.y + e4.y;
      float gv = g4.z + e4.z, ov = g4.w + e4.w;
      float ig = 1.0f / (1.0f + expf(-iv));
      float fg = 1.0f / (1.0f + expf(-fv));
      float gg = tanhf(gv);
      float og = 1.0f / (1.0f + expf(-ov));
      const size_t ci = (size_t)grow * Hsz + jglob;
      float cn = fg * cF[ci] + ig * gg;
      float hn = og * tanhf(cn);
      cF[ci] = cn;
      h_out[ci] = hn;
      ushort_t hi = f2bf_hi(hn);
      Aout[(size_t)grow * 1024 + jglob] = hi;
      Aout[(size_t)grow * 1024 + 512 + jglob] = f2bf_hi(hn - bf2f(hi));
    }
  }
}

// ---------------- decoders + gumbel sampling (wave per row) ----------------
template <int K>
__global__ __launch_bounds__(256) void decide_step(
    const float* __restrict__ h, const float* __restrict__ wn,
    const float* __restrict__ bn, const float* __restrict__ wopi,
    const float* __restrict__ bopi, const float* __restrict__ gum,
    float* __restrict__ oan, float* __restrict__ oao,
    float* __restrict__ oln, float* __restrict__ olo,
    float* __restrict__ oen, float* __restrict__ oeo,
    int* __restrict__ act_next, const int* __restrict__ hidx, int hmode,
    const int* __restrict__ cls_prev, int* __restrict__ cls_out) {
  const int lane = threadIdx.x & 63;
  const int r = (blockIdx.x << 2) + (threadIdx.x >> 6);
  const int idx = (hmode == 0) ? 0 : (hmode == 1 ? r : hidx[r]);
  const float* hr = h + (size_t)idx * Hsz;
  const float4 hv0 = *(const float4*)(hr + (lane << 3));
  const float4 hv1 = *(const float4*)(hr + (lane << 3) + 4);

  float nl[K];
#pragma unroll
  for (int j = 0; j < K; ++j) {
    const float* w = wn + (size_t)j * Hsz;
    float4 w0 = *(const float4*)(w + (lane << 3));
    float4 w1 = *(const float4*)(w + (lane << 3) + 4);
    float v = hv0.x * w0.x + hv0.y * w0.y + hv0.z * w0.z + hv0.w * w0.w +
              hv1.x * w1.x + hv1.y * w1.y + hv1.z * w1.z + hv1.w * w1.w;
#pragma unroll
    for (int off = 32; off > 0; off >>= 1) v += __shfl_xor(v, off, 64);
    nl[j] = 2.5f * tanhf((v + bn[j]) / 5.0f);
  }
  float ol[8];
#pragma unroll
  for (int j = 0; j < 8; ++j) {
    const float* w = wopi + (size_t)j * Hsz;
    float4 w0 = *(const float4*)(w + (lane << 3));
    float4 w1 = *(const float4*)(w + (lane << 3) + 4);
    float v = hv0.x * w0.x + hv0.y * w0.y + hv0.z * w0.z + hv0.w * w0.w +
              hv1.x * w1.x + hv1.y * w1.y + hv1.z * w1.z + hv1.w * w1.w;
#pragma unroll
    for (int off = 32; off > 0; off >>= 1) v += __shfl_xor(v, off, 64);
    ol[j] = (v + bopi[j]) / 5.0f;
  }

  {
    const float* g = gum + (size_t)r * 8;
    float m = nl[0];
#pragma unroll
    for (int j = 1; j < K; ++j) m = fmaxf(m, nl[j]);
    float se = 0.0f;
#pragma unroll
    for (int j = 0; j < K; ++j) se += expf(nl[j] - m);
    float lse = logf(se);
    int a = 0;
    float best = nl[0] + g[0];
#pragma unroll
    for (int j = 1; j < K; ++j) {
      float v = nl[j] + g[j];
      if (v > best) { best = v; a = j; }
    }
    float ent = 0.0f, sel = 0.0f;
#pragma unroll
    for (int j = 0; j < K; ++j) {
      float lp = nl[j] - m - lse;
      ent -= lp * expf(lp);
      if (j == a) sel = lp;
    }
    if (lane == 0) { oan[r] = (float)a; oln[r] = sel; oen[r] = ent; }
  }
  {
    const float* g = gum + (size_t)Bsz * 8 + (size_t)r * 8;
    float m = ol[0];
#pragma unroll
    for (int j = 1; j < 8; ++j) m = fmaxf(m, ol[j]);
    float se = 0.0f;
#pragma unroll
    for (int j = 0; j < 8; ++j) se += expf(ol[j] - m);
    float lse = logf(se);
    int a = 0;
    float best = ol[0] + g[0];
#pragma unroll
    for (int j = 1; j < 8; ++j) {
      float v = ol[j] + g[j];
      if (v > best) { best = v; a = j; }
    }
    float ent = 0.0f, sel = 0.0f;
#pragma unroll
    for (int j = 0; j < 8; ++j) {
      float lp = ol[j] - m - lse;
      ent -= lp * expf(lp);
      if (j == a) sel = lp;
    }
    if (lane == 0) {
      oao[r] = (float)a; olo[r] = sel; oeo[r] = ent;
      act_next[r] = a;
      if (cls_out) cls_out[r] = (cls_prev ? cls_prev[r] * 8 : 0) + a;
    }
  }
}

// ---------------------------------------------------------------------------
extern "C" void kernel_launch(void* const* d_in, const int* in_sizes, int n_in,
                              void* d_out, int out_size, void* d_ws,
                              size_t ws_size, hipStream_t stream) {
  (void)in_sizes; (void)n_in; (void)out_size; (void)ws_size;
  const float* emb = (const float*)d_in[0];
  const float* w_ih = (const float*)d_in[1];
  const float* w_hh = (const float*)d_in[2];
  const float* b_ih = (const float*)d_in[3];
  const float* b_hh = (const float*)d_in[4];
  const float* wn[4] = {(const float*)d_in[5], (const float*)d_in[7],
                        (const float*)d_in[9], (const float*)d_in[11]};
  const float* bn[4] = {(const float*)d_in[6], (const float*)d_in[8],
                        (const float*)d_in[10], (const float*)d_in[12]};
  const float* wop = (const float*)d_in[13];
  const float* bop = (const float*)d_in[14];
  const float* gum = (const float*)d_in[15];

  float* ws = (float*)d_ws;
  float* E = ws;                 ws += 9 * G4H;
  float* Eperm = ws;             ws += 9 * G4H;
  float* h1 = ws;                ws += Hsz;
  float* c1 = ws;                ws += Hsz;
  float* h2 = ws;                ws += 8 * Hsz;
  float* c2 = ws;                ws += 8 * Hsz;
  float* h3 = ws;                ws += 64 * Hsz;
  float* c3 = ws;                ws += 64 * Hsz;
  float* h4 = ws;                ws += 512 * Hsz;
  float* c4 = ws;                ws += 512 * Hsz;
  float* Gearly = ws;            // 4 MB used by early path...
  ushort_t* AcatB = (ushort_t*)Gearly;  // ...region reused (8 MB) from step 5
  ws += (8u << 20) / 4;
  ushort_t* AcatA = (ushort_t*)ws;      ws += (8u << 20) / 4;
  ushort_t* Wcat = (ushort_t*)ws;       ws += (6u << 20) / 4;
  float* hA = ws;                ws += (size_t)Bsz * Hsz;
  float* cF = ws;                ws += (size_t)Bsz * Hsz;
  int* act = (int*)ws;
  int* cls = act + Bsz;

  float* out = (float*)d_out;
  const size_t SZ = (size_t)16 * Bsz;

  auto decide = [&](int s, const float* h, int hmode, const int* hidx,
                    const int* cls_prev, int* cls_out) {
    const int i = s >> 1;
    float* oan = out + (size_t)(2 * s) * Bsz;
    float* oao = out + (size_t)(2 * s + 1) * Bsz;
    float* oln = out + SZ + (size_t)(2 * s) * Bsz;
    float* olo = out + SZ + (size_t)(2 * s + 1) * Bsz;
    float* oen = out + 2 * SZ + (size_t)(2 * s) * Bsz;
    float* oeo = out + 2 * SZ + (size_t)(2 * s + 1) * Bsz;
    const float* gn = gum + (size_t)(2 * s) * Bsz * 8;
    const float* wopi = wop + (size_t)i * 8 * Hsz;
    const float* bopi = bop + (size_t)i * 8;
    switch (i) {
      case 0:
        decide_step<2><<<Bsz / 4, 256, 0, stream>>>(h, wn[0], bn[0], wopi, bopi,
            gn, oan, oao, oln, olo, oen, oeo, act, hidx, hmode, cls_prev, cls_out);
        break;
      case 1:
        decide_step<3><<<Bsz / 4, 256, 0, stream>>>(h, wn[1], bn[1], wopi, bopi,
            gn, oan, oao, oln, olo, oen, oeo, act, hidx, hmode, cls_prev, cls_out);
        break;
      case 2:
        decide_step<4><<<Bsz / 4, 256, 0, stream>>>(h, wn[2], bn[2], wopi, bopi,
            gn, oan, oao, oln, olo, oen, oeo, act, hidx, hmode, cls_prev, cls_out);
        break;
      default:
        decide_step<5><<<Bsz / 4, 256, 0, stream>>>(h, wn[3], bn[3], wopi, bopi,
            gn, oan, oao, oln, olo, oen, oeo, act, hidx, hmode, cls_prev, cls_out);
        break;
    }
  };

  precompute_E<<<(9 * G4H) / 256, 256, 0, stream>>>(emb, w_ih, b_ih, b_hh, E,
                                                    Eperm);
  build_wcat<<<dim3(6, 2048), 256, 0, stream>>>(w_hh, Wcat);

  // step 0: gates = E[0] uniform -> 1-class h1,c1
  step_pw<<<2, 256, 0, stream>>>(nullptr, E, nullptr, h1, c1, 1);
  decide(0, h1, 0, nullptr, nullptr, cls);

  // step 1: 1-class GEMM -> 8-class h2,c2
  class_gemm<<<512, 256, 0, stream>>>(h1, w_hh, Gearly, 1);
  step_pw<<<16, 256, 0, stream>>>(Gearly, E, c1, h2, c2, 8);
  decide(1, h2, 2, cls, cls, cls);

  // step 2: 8-class GEMM -> 64-class h3,c3
  class_gemm<<<4096, 256, 0, stream>>>(h2, w_hh, Gearly, 8);
  step_pw<<<128, 256, 0, stream>>>(Gearly, E, c2, h3, c3, 64);
  decide(2, h3, 2, cls, cls, cls);

  // step 3: 64-class GEMM -> 512-class h4,c4
  class_gemm<<<32768, 256, 0, stream>>>(h3, w_hh, Gearly, 64);
  step_pw<<<1024, 256, 0, stream>>>(Gearly, E, c3, h4, c4, 512);
  decide(3, h4, 2, cls, nullptr, nullptr);

  // step 4: 512-class GEMM, expand to full rows (+ emit AcatA for step 5)
  gemm64<<<256, 256, 0, stream>>>(h4, w_hh, Gearly);
  expand_pw<<<(Bsz * Hsz) / 256, 256, 0, stream>>>(Gearly, E, c4, cls, act, hA,
                                                   cF, AcatA);
  decide(4, hA, 1, nullptr, nullptr, nullptr);

  // steps 5-7: split-bf16 MFMA GEMM + fused pointwise (A-cat ping-pong)
  ushort_t* ain = AcatA;
  ushort_t* aout = AcatB;
  for (int s = 5; s < 8; ++s) {
    gemm_bf16_lstm<<<512, 256, 0, stream>>>(ain, Wcat, Eperm, act, cF, hA, aout);
    decide(s, hA, 1, nullptr, nullptr, nullptr);
    ushort_t* t = ain; ain = aout; aout = t;
  }
}

// Round 2
// 395.035 us; speedup vs baseline: 1.2266x; 1.0572x over previous
//
#include <hip/hip_runtime.h>

// ---------------------------------------------------------------------------
// NASNet controller: 8 sequential LSTM steps (B=4096, H=512) + 16 decisions.
//  - Steps 1-4 run on class representatives (1/8/64/512 rows): rows only
//    differ through sampled op tokens (8^s classes).
//  - Steps 5-7: full GEMMs on the MFMA pipe via split-bf16 (hi+lo) emulation:
//    C = Ahi@Whi + Ahi@Wlo + Alo@Whi.
//  - R5: double-buffered LDS prefetch (1 barrier/iter) + XCD superblock
//    blockIdx swizzle (per-XCD working set ~fits its 4MB L2).
//  - R6: shared-operand super-iteration: per K=32 slice stage {Ahi,Alo,Whi,Wlo}
//    panels, read each fragment ONCE into registers, issue all 3 products
//    (48 MFMA per 16 ds_read_b128). -33% LDS + staging traffic vs R5; dense
//    [128][32] panels make every ds_read_b128 a contiguous 1KB wave read
//    (conflict-free, no swizzle). Step-3 class GEMM -> tiled gemm64 (M=64);
//    precompute_E -> wave-per-output coalesced reduction.
// ---------------------------------------------------------------------------

constexpr int Bsz = 4096;
constexpr int Hsz = 512;
constexpr int G4H = 2048;

typedef unsigned short ushort_t;
using short8 = __attribute__((ext_vector_type(8))) short;
using f32x4 = __attribute__((ext_vector_type(4))) float;

__device__ __forceinline__ ushort_t f2bf_hi(float f) {
  unsigned u = __float_as_uint(f);
  u += 0x7FFF + ((u >> 16) & 1);  // RNE
  return (ushort_t)(u >> 16);
}
__device__ __forceinline__ float bf2f(ushort_t h) {
  return __uint_as_float((unsigned)h << 16);
}

__device__ __forceinline__ void glds16(const void* gsrc, void* ldst) {
  __builtin_amdgcn_global_load_lds(
      (const __attribute__((address_space(1))) void*)gsrc,
      (__attribute__((address_space(3))) void*)ldst, 16, 0, 0);
}

// ---------------- E = emb @ w_ih^T + b_ih + b_hh (std + ct-permuted) -------
// R6: wave-per-output (coalesced 2KB row reads + shfl reduce).
__global__ __launch_bounds__(256) void precompute_E(
    const float* __restrict__ emb, const float* __restrict__ w_ih,
    const float* __restrict__ b_ih, const float* __restrict__ b_hh,
    float* __restrict__ E, float* __restrict__ Eperm) {
  const int lane = threadIdx.x & 63;
  const int wid = (blockIdx.x << 2) + (threadIdx.x >> 6);  // t*2048 + col
  const int t = wid >> 11;
  const int col = wid & 2047;
  const float* er = emb + (size_t)t * Hsz + (lane << 3);
  const float* wr = w_ih + (size_t)col * Hsz + (lane << 3);
  float4 e0 = *(const float4*)(er);
  float4 e1 = *(const float4*)(er + 4);
  float4 w0 = *(const float4*)(wr);
  float4 w1 = *(const float4*)(wr + 4);
  float v = e0.x * w0.x + e0.y * w0.y + e0.z * w0.z + e0.w * w0.w +
            e1.x * w1.x + e1.y * w1.y + e1.z * w1.z + e1.w * w1.w;
#pragma unroll
  for (int off = 32; off > 0; off >>= 1) v += __shfl_xor(v, off, 64);
  if (lane == 0) {
    float val = v + b_ih[col] + b_hh[col];
    E[wid] = val;
    int g = col >> 9, j = col & 511;
    Eperm[(size_t)t * G4H + (j << 2) + g] = val;
  }
}

// ---------------- W_cat: [2048 ct rows][1024 used] bf16 = [hi | lo] --------
__global__ __launch_bounds__(256) void build_wcat(
    const float* __restrict__ w_hh, ushort_t* __restrict__ Wcat) {
  int ct = blockIdx.y;
  int k = blockIdx.x * 256 + threadIdx.x;  // 0..1023
  int j = ct >> 2, g = ct & 3;
  const float* srcrow = w_hh + (size_t)(g * 512 + j) * Hsz;
  ushort_t out;
  if (k < 512) {
    out = f2bf_hi(srcrow[k]);
  } else {
    float x = srcrow[k - 512];
    ushort_t hi = f2bf_hi(x);
    out = f2bf_hi(x - bf2f(hi));
  }
  Wcat[(size_t)ct * 1536 + k] = out;
}

// ---------------- class GEMM: G[q][col] = dot(h[q], w[col]) ----------------
__global__ __launch_bounds__(256) void class_gemm(
    const float* __restrict__ h, const float* __restrict__ w,
    float* __restrict__ G, int nq) {
  const int wid = (blockIdx.x << 2) + (threadIdx.x >> 6);
  const int lane = threadIdx.x & 63;
  const int q = wid >> 11;
  const int col = wid & 2047;
  if (q >= nq) return;
  const float* hr = h + (size_t)q * Hsz + (lane << 3);
  const float* wr = w + (size_t)col * Hsz + (lane << 3);
  float4 a0 = *(const float4*)(hr);
  float4 a1 = *(const float4*)(hr + 4);
  float4 b0 = *(const float4*)(wr);
  float4 b1 = *(const float4*)(wr + 4);
  float v = a0.x * b0.x + a0.y * b0.y + a0.z * b0.z + a0.w * b0.w +
            a1.x * b1.x + a1.y * b1.y + a1.z * b1.z + a1.w * b1.w;
#pragma unroll
  for (int off = 32; off > 0; off >>= 1) v += __shfl_xor(v, off, 64);
  if (lane == 0) G[(size_t)q * G4H + col] = v;
}

// ---------------- 64x64-tiled fp32 GEMM (steps 3/4, M=64/512) --------------
__global__ __launch_bounds__(256) void gemm64(
    const float* __restrict__ A, const float* __restrict__ Bw,
    float* __restrict__ G) {
  constexpr int LDA = 68;
  __shared__ float As[16 * LDA];
  __shared__ float Bs[16 * LDA];
  const int tid = threadIdx.x;
  const int bx = blockIdx.x & 31;
  const int by = blockIdx.x >> 5;
  const int r0 = by * 64, c0 = bx * 64;
  const int tx = tid & 15, ty = tid >> 4;
  const int lr = tid >> 2;
  const int lk = (tid & 3) << 2;
  const float* Ar = A + (size_t)(r0 + lr) * Hsz;
  const float* Br = Bw + (size_t)(c0 + lr) * Hsz;
  float acc[4][4];
#pragma unroll
  for (int i = 0; i < 4; ++i)
#pragma unroll
    for (int j = 0; j < 4; ++j) acc[i][j] = 0.0f;

  for (int k0 = 0; k0 < Hsz; k0 += 16) {
    float4 a = *(const float4*)(Ar + k0 + lk);
    float4 b = *(const float4*)(Br + k0 + lk);
    __syncthreads();
    As[(lk + 0) * LDA + lr] = a.x;
    As[(lk + 1) * LDA + lr] = a.y;
    As[(lk + 2) * LDA + lr] = a.z;
    As[(lk + 3) * LDA + lr] = a.w;
    Bs[(lk + 0) * LDA + lr] = b.x;
    Bs[(lk + 1) * LDA + lr] = b.y;
    Bs[(lk + 2) * LDA + lr] = b.z;
    Bs[(lk + 3) * LDA + lr] = b.w;
    __syncthreads();
#pragma unroll
    for (int kk = 0; kk < 16; ++kk) {
      float4 av = *(const float4*)&As[kk * LDA + (ty << 2)];
      float4 bv = *(const float4*)&Bs[kk * LDA + (tx << 2)];
      float avs[4] = {av.x, av.y, av.z, av.w};
      float bvs[4] = {bv.x, bv.y, bv.z, bv.w};
#pragma unroll
      for (int i = 0; i < 4; ++i)
#pragma unroll
        for (int j = 0; j < 4; ++j) acc[i][j] = fmaf(avs[i], bvs[j], acc[i][j]);
    }
  }
#pragma unroll
  for (int i = 0; i < 4; ++i)
#pragma unroll
    for (int j = 0; j < 4; ++j)
      G[(size_t)(r0 + (ty << 2) + i) * G4H + c0 + (tx << 2) + j] = acc[i][j];
}

// ---------------- class pointwise ------------------------------------------
__global__ __launch_bounds__(256) void step_pw(
    const float* __restrict__ G, const float* __restrict__ E,
    const float* __restrict__ c_prev, float* __restrict__ h_out,
    float* __restrict__ c_out, int nq) {
  int idx = blockIdx.x * 256 + threadIdx.x;
  if (idx >= nq * Hsz) return;
  int q = idx >> 9, j = idx & 511;
  int gq = q >> 3, er = q & 7;
  const float* Eg = E + (size_t)er * G4H;
  float iv = Eg[j], fv = Eg[512 + j], gv = Eg[1024 + j], ov = Eg[1536 + j];
  if (G) {
    const float* Gg = G + (size_t)gq * G4H;
    iv += Gg[j]; fv += Gg[512 + j]; gv += Gg[1024 + j]; ov += Gg[1536 + j];
  }
  float cp = c_prev ? c_prev[(size_t)gq * Hsz + j] : 0.0f;
  float ig = 1.0f / (1.0f + expf(-iv));
  float fg = 1.0f / (1.0f + expf(-fv));
  float gg = tanhf(gv);
  float og = 1.0f / (1.0f + expf(-ov));
  float cn = fg * cp + ig * gg;
  c_out[idx] = cn;
  h_out[idx] = og * tanhf(cn);
}

// ---------------- step-4 expansion: classes (512) -> rows (4096) -----------
__global__ __launch_bounds__(256) void expand_pw(
    const float* __restrict__ G, const float* __restrict__ E,
    const float* __restrict__ c4, const int* __restrict__ cls3,
    const int* __restrict__ act3, float* __restrict__ h_out,
    float* __restrict__ c_out, ushort_t* __restrict__ Acat) {
  int idx = blockIdx.x * 256 + threadIdx.x;
  int r = idx >> 9, j = idx & 511;
  int q = cls3[r], er = act3[r];
  const float* Eg = E + (size_t)er * G4H;
  const float* Gg = G + (size_t)q * G4H;
  float iv = Gg[j] + Eg[j];
  float fv = Gg[512 + j] + Eg[512 + j];
  float gv = Gg[1024 + j] + Eg[1024 + j];
  float ov = Gg[1536 + j] + Eg[1536 + j];
  float cp = c4[(size_t)q * Hsz + j];
  float ig = 1.0f / (1.0f + expf(-iv));
  float fg = 1.0f / (1.0f + expf(-fv));
  float gg = tanhf(gv);
  float og = 1.0f / (1.0f + expf(-ov));
  float cn = fg * cp + ig * gg;
  float hn = og * tanhf(cn);
  c_out[idx] = cn;
  h_out[idx] = hn;
  ushort_t hi = f2bf_hi(hn);
  Acat[(size_t)r * 1024 + j] = hi;
  Acat[(size_t)r * 1024 + 512 + j] = f2bf_hi(hn - bf2f(hi));
}

// ---------------- split-bf16 MFMA GEMM + fused LSTM pointwise --------------
// C[4096 x 2048ct] = Ahi@Whi + Ahi@Wlo + Alo@Whi  (per K=32 super-iteration)
// tile 128x128, 4 waves x (4x4 16x16x32 tiles). Panels: [128 rows][32 K] bf16.
// Fragments read once per super-iter; 48 MFMA per 16 ds_read_b128.
__global__ __launch_bounds__(256) void gemm_bf16_lstm(
    const ushort_t* __restrict__ Acat, const ushort_t* __restrict__ Wcat,
    const float* __restrict__ Eperm, const int* __restrict__ act,
    float* __restrict__ cF, float* __restrict__ h_out,
    ushort_t* __restrict__ Aout) {
  __shared__ union {
    ushort_t P[2][4][128 * 32];  // [buf][AH,AL,BH,BL][row*32+k] = 64 KB
    float C[64 * 132];           // 33.8 KB epilogue staging
  } sm;

  const int tid = threadIdx.x;
  const int wave = tid >> 6, lane = tid & 63;
  // XCD-aware superblock swizzle (bijective: 512 = 8 XCD x 64).
  const int xcd = blockIdx.x & 7;
  const int i64 = blockIdx.x >> 3;
  const int by = ((xcd >> 1) << 3) + (i64 >> 3);  // 32 row tiles
  const int bx = ((xcd & 1) << 3) + (i64 & 7);    // 16 col tiles
  const int r0 = by * 128, c0 = bx * 128;
  const int wr = (wave >> 1) * 64, wc = (wave & 1) * 64;
  const int mrow = lane & 15, quad = lane >> 4;

  // staging: one glds16 fills a 1KB region = 16 rows x 32 K of one panel.
  // lane l -> row l>>2, 16B chunk l&3 (dest = uniform base + lane*16 by HW;
  // resulting layout is exactly row-major [128][32] bf16).
  const int srow = lane >> 2;      // 0..15 within region
  const int sk = (lane & 3) << 3;  // k-element offset 0,8,16,24

  // per-thread precomputed source pointers + dest offsets for the 8 stages
  const ushort_t* sbase[8];
  int doff[8];
#pragma unroll
  for (int q = 0; q < 8; ++q) {
    const int g = (q << 2) + wave;   // 0..31 unique
    const int panel = g >> 3;        // 0=AH 1=AL 2=BH 3=BL
    const int region = g & 7;
    const int row = region * 16 + srow;
    if (panel == 0)
      sbase[q] = Acat + (size_t)(r0 + row) * 1024 + sk;
    else if (panel == 1)
      sbase[q] = Acat + (size_t)(r0 + row) * 1024 + 512 + sk;
    else if (panel == 2)
      sbase[q] = Wcat + (size_t)(c0 + row) * 1536 + sk;
    else
      sbase[q] = Wcat + (size_t)(c0 + row) * 1536 + 512 + sk;
    doff[q] = panel * 8192 + region * 1024;  // byte offset within buffer
  }

  f32x4 acc[4][4];
#pragma unroll
  for (int i = 0; i < 4; ++i)
#pragma unroll
    for (int jt = 0; jt < 4; ++jt) acc[i][jt] = (f32x4){0.f, 0.f, 0.f, 0.f};

  auto stage = [&](int buf, int it) {
    const int ks = it << 5;  // K-element offset
#pragma unroll
    for (int q = 0; q < 8; ++q)
      glds16(sbase[q] + ks, (char*)sm.P[0][0] + (buf << 15) + doff[q]);
  };

  // prologue
  stage(0, 0);
  __syncthreads();

  int cur = 0;
  for (int it = 0; it < 16; ++it) {
    if (it < 15) stage(cur ^ 1, it + 1);  // prefetch next K-slice
    const ushort_t* AH = sm.P[cur][0];
    const ushort_t* AL = sm.P[cur][1];
    const ushort_t* BH = sm.P[cur][2];
    const ushort_t* BL = sm.P[cur][3];
    short8 ah[4], al[4], bh[4], bl[4];
#pragma unroll
    for (int i = 0; i < 4; ++i) {
      ah[i] = *(const short8*)&AH[(wr + i * 16 + mrow) * 32 + (quad << 3)];
      al[i] = *(const short8*)&AL[(wr + i * 16 + mrow) * 32 + (quad << 3)];
    }
#pragma unroll
    for (int jt = 0; jt < 4; ++jt) {
      bh[jt] = *(const short8*)&BH[(wc + jt * 16 + mrow) * 32 + (quad << 3)];
      bl[jt] = *(const short8*)&BL[(wc + jt * 16 + mrow) * 32 + (quad << 3)];
    }
#pragma unroll
    for (int i = 0; i < 4; ++i)
#pragma unroll
      for (int jt = 0; jt < 4; ++jt) {
        acc[i][jt] = __builtin_amdgcn_mfma_f32_16x16x32_bf16(
            ah[i], bh[jt], acc[i][jt], 0, 0, 0);
        acc[i][jt] = __builtin_amdgcn_mfma_f32_16x16x32_bf16(
            ah[i], bl[jt], acc[i][jt], 0, 0, 0);
        acc[i][jt] = __builtin_amdgcn_mfma_f32_16x16x32_bf16(
            al[i], bh[jt], acc[i][jt], 0, 0, 0);
      }
    __syncthreads();  // drains prefetch + protects buffer reuse
    cur ^= 1;
  }

  // ---- epilogue: two 64-row phases through LDS, fused LSTM pointwise ----
  const int jj = tid & 31;         // j-local 0..31
  const int rbase = tid >> 5;      // 0..7
#pragma unroll
  for (int p = 0; p < 2; ++p) {
    __syncthreads();  // phase 0: K-loop reads done; phase 1: prev consume done
    if ((wr >> 6) == p) {
#pragma unroll
      for (int i = 0; i < 4; ++i)
#pragma unroll
        for (int jt = 0; jt < 4; ++jt)
#pragma unroll
          for (int rg = 0; rg < 4; ++rg)
            sm.C[(i * 16 + quad * 4 + rg) * 132 + wc + jt * 16 + mrow] =
                acc[i][jt][rg];
    }
    __syncthreads();
#pragma unroll
    for (int rp = 0; rp < 8; ++rp) {
      const int rl = rbase * 8 + rp;           // 0..63
      const int grow = r0 + p * 64 + rl;
      float4 g4 = *(float4*)&sm.C[rl * 132 + jj * 4];
      const int a = act[grow];
      const int jglob = (c0 >> 2) + jj;        // 0..511
      float4 e4 = *(const float4*)&Eperm[(size_t)a * G4H + c0 + jj * 4];
      float iv = g4.x + e4.x, fv = g4.y + e4.y;
      float gv = g4.z + e4.z, ov = g4.w + e4.w;
      float ig = 1.0f / (1.0f + expf(-iv));
      float fg = 1.0f / (1.0f + expf(-fv));
      float gg = tanhf(gv);
      float og = 1.0f / (1.0f + expf(-ov));
      const size_t ci = (size_t)grow * Hsz + jglob;
      float cn = fg * cF[ci] + ig * gg;
      float hn = og * tanhf(cn);
      cF[ci] = cn;
      h_out[ci] = hn;
      ushort_t hi = f2bf_hi(hn);
      Aout[(size_t)grow * 1024 + jglob] = hi;
      Aout[(size_t)grow * 1024 + 512 + jglob] = f2bf_hi(hn - bf2f(hi));
    }
  }
}

// ---------------- decoders + gumbel sampling (wave per row) ----------------
template <int K>
__global__ __launch_bounds__(256) void decide_step(
    const float* __restrict__ h, const float* __restrict__ wn,
    const float* __restrict__ bn, const float* __restrict__ wopi,
    const float* __restrict__ bopi, const float* __restrict__ gum,
    float* __restrict__ oan, float* __restrict__ oao,
    float* __restrict__ oln, float* __restrict__ olo,
    float* __restrict__ oen, float* __restrict__ oeo,
    int* __restrict__ act_next, const int* __restrict__ hidx, int hmode,
    const int* __restrict__ cls_prev, int* __restrict__ cls_out) {
  const int lane = threadIdx.x & 63;
  const int r = (blockIdx.x << 2) + (threadIdx.x >> 6);
  const int idx = (hmode == 0) ? 0 : (hmode == 1 ? r : hidx[r]);
  const float* hr = h + (size_t)idx * Hsz;
  const float4 hv0 = *(const float4*)(hr + (lane << 3));
  const float4 hv1 = *(const float4*)(hr + (lane << 3) + 4);

  float nl[K];
#pragma unroll
  for (int j = 0; j < K; ++j) {
    const float* w = wn + (size_t)j * Hsz;
    float4 w0 = *(const float4*)(w + (lane << 3));
    float4 w1 = *(const float4*)(w + (lane << 3) + 4);
    float v = hv0.x * w0.x + hv0.y * w0.y + hv0.z * w0.z + hv0.w * w0.w +
              hv1.x * w1.x + hv1.y * w1.y + hv1.z * w1.z + hv1.w * w1.w;
#pragma unroll
    for (int off = 32; off > 0; off >>= 1) v += __shfl_xor(v, off, 64);
    nl[j] = 2.5f * tanhf((v + bn[j]) / 5.0f);
  }
  float ol[8];
#pragma unroll
  for (int j = 0; j < 8; ++j) {
    const float* w = wopi + (size_t)j * Hsz;
    float4 w0 = *(const float4*)(w + (lane << 3));
    float4 w1 = *(const float4*)(w + (lane << 3) + 4);
    float v = hv0.x * w0.x + hv0.y * w0.y + hv0.z * w0.z + hv0.w * w0.w +
              hv1.x * w1.x + hv1.y * w1.y + hv1.z * w1.z + hv1.w * w1.w;
#pragma unroll
    for (int off = 32; off > 0; off >>= 1) v += __shfl_xor(v, off, 64);
    ol[j] = (v + bopi[j]) / 5.0f;
  }

  {
    const float* g = gum + (size_t)r * 8;
    float m = nl[0];
#pragma unroll
    for (int j = 1; j < K; ++j) m = fmaxf(m, nl[j]);
    float se = 0.0f;
#pragma unroll
    for (int j = 0; j < K; ++j) se += expf(nl[j] - m);
    float lse = logf(se);
    int a = 0;
    float best = nl[0] + g[0];
#pragma unroll
    for (int j = 1; j < K; ++j) {
      float v = nl[j] + g[j];
      if (v > best) { best = v; a = j; }
    }
    float ent = 0.0f, sel = 0.0f;
#pragma unroll
    for (int j = 0; j < K; ++j) {
      float lp = nl[j] - m - lse;
      ent -= lp * expf(lp);
      if (j == a) sel = lp;
    }
    if (lane == 0) { oan[r] = (float)a; oln[r] = sel; oen[r] = ent; }
  }
  {
    const float* g = gum + (size_t)Bsz * 8 + (size_t)r * 8;
    float m = ol[0];
#pragma unroll
    for (int j = 1; j < 8; ++j) m = fmaxf(m, ol[j]);
    float se = 0.0f;
#pragma unroll
    for (int j = 0; j < 8; ++j) se += expf(ol[j] - m);
    float lse = logf(se);
    int a = 0;
    float best = ol[0] + g[0];
#pragma unroll
    for (int j = 1; j < 8; ++j) {
      float v = ol[j] + g[j];
      if (v > best) { best = v; a = j; }
    }
    float ent = 0.0f, sel = 0.0f;
#pragma unroll
    for (int j = 0; j < 8; ++j) {
      float lp = ol[j] - m - lse;
      ent -= lp * expf(lp);
      if (j == a) sel = lp;
    }
    if (lane == 0) {
      oao[r] = (float)a; olo[r] = sel; oeo[r] = ent;
      act_next[r] = a;
      if (cls_out) cls_out[r] = (cls_prev ? cls_prev[r] * 8 : 0) + a;
    }
  }
}

// ---------------------------------------------------------------------------
extern "C" void kernel_launch(void* const* d_in, const int* in_sizes, int n_in,
                              void* d_out, int out_size, void* d_ws,
                              size_t ws_size, hipStream_t stream) {
  (void)in_sizes; (void)n_in; (void)out_size; (void)ws_size;
  const float* emb = (const float*)d_in[0];
  const float* w_ih = (const float*)d_in[1];
  const float* w_hh = (const float*)d_in[2];
  const float* b_ih = (const float*)d_in[3];
  const float* b_hh = (const float*)d_in[4];
  const float* wn[4] = {(const float*)d_in[5], (const float*)d_in[7],
                        (const float*)d_in[9], (const float*)d_in[11]};
  const float* bn[4] = {(const float*)d_in[6], (const float*)d_in[8],
                        (const float*)d_in[10], (const float*)d_in[12]};
  const float* wop = (const float*)d_in[13];
  const float* bop = (const float*)d_in[14];
  const float* gum = (const float*)d_in[15];

  float* ws = (float*)d_ws;
  float* E = ws;                 ws += 9 * G4H;
  float* Eperm = ws;             ws += 9 * G4H;
  float* h1 = ws;                ws += Hsz;
  float* c1 = ws;                ws += Hsz;
  float* h2 = ws;                ws += 8 * Hsz;
  float* c2 = ws;                ws += 8 * Hsz;
  float* h3 = ws;                ws += 64 * Hsz;
  float* c3 = ws;                ws += 64 * Hsz;
  float* h4 = ws;                ws += 512 * Hsz;
  float* c4 = ws;                ws += 512 * Hsz;
  float* Gearly = ws;            // 4 MB used by early path...
  ushort_t* AcatB = (ushort_t*)Gearly;  // ...region reused (8 MB) from step 5
  ws += (8u << 20) / 4;
  ushort_t* AcatA = (ushort_t*)ws;      ws += (8u << 20) / 4;
  ushort_t* Wcat = (ushort_t*)ws;       ws += (6u << 20) / 4;
  float* hA = ws;                ws += (size_t)Bsz * Hsz;
  float* cF = ws;                ws += (size_t)Bsz * Hsz;
  int* act = (int*)ws;
  int* cls = act + Bsz;

  float* out = (float*)d_out;
  const size_t SZ = (size_t)16 * Bsz;

  auto decide = [&](int s, const float* h, int hmode, const int* hidx,
                    const int* cls_prev, int* cls_out) {
    const int i = s >> 1;
    float* oan = out + (size_t)(2 * s) * Bsz;
    float* oao = out + (size_t)(2 * s + 1) * Bsz;
    float* oln = out + SZ + (size_t)(2 * s) * Bsz;
    float* olo = out + SZ + (size_t)(2 * s + 1) * Bsz;
    float* oen = out + 2 * SZ + (size_t)(2 * s) * Bsz;
    float* oeo = out + 2 * SZ + (size_t)(2 * s + 1) * Bsz;
    const float* gn = gum + (size_t)(2 * s) * Bsz * 8;
    const float* wopi = wop + (size_t)i * 8 * Hsz;
    const float* bopi = bop + (size_t)i * 8;
    switch (i) {
      case 0:
        decide_step<2><<<Bsz / 4, 256, 0, stream>>>(h, wn[0], bn[0], wopi, bopi,
            gn, oan, oao, oln, olo, oen, oeo, act, hidx, hmode, cls_prev, cls_out);
        break;
      case 1:
        decide_step<3><<<Bsz / 4, 256, 0, stream>>>(h, wn[1], bn[1], wopi, bopi,
            gn, oan, oao, oln, olo, oen, oeo, act, hidx, hmode, cls_prev, cls_out);
        break;
      case 2:
        decide_step<4><<<Bsz / 4, 256, 0, stream>>>(h, wn[2], bn[2], wopi, bopi,
            gn, oan, oao, oln, olo, oen, oeo, act, hidx, hmode, cls_prev, cls_out);
        break;
      default:
        decide_step<5><<<Bsz / 4, 256, 0, stream>>>(h, wn[3], bn[3], wopi, bopi,
            gn, oan, oao, oln, olo, oen, oeo, act, hidx, hmode, cls_prev, cls_out);
        break;
    }
  };

  precompute_E<<<(9 * G4H) / 4, 256, 0, stream>>>(emb, w_ih, b_ih, b_hh, E,
                                                  Eperm);
  build_wcat<<<dim3(4, 2048), 256, 0, stream>>>(w_hh, Wcat);

  // step 0: gates = E[0] uniform -> 1-class h1,c1
  step_pw<<<2, 256, 0, stream>>>(nullptr, E, nullptr, h1, c1, 1);
  decide(0, h1, 0, nullptr, nullptr, cls);

  // step 1: 1-class GEMM -> 8-class h2,c2
  class_gemm<<<512, 256, 0, stream>>>(h1, w_hh, Gearly, 1);
  step_pw<<<16, 256, 0, stream>>>(Gearly, E, c1, h2, c2, 8);
  decide(1, h2, 2, cls, cls, cls);

  // step 2: 8-class GEMM -> 64-class h3,c3
  class_gemm<<<4096, 256, 0, stream>>>(h2, w_hh, Gearly, 8);
  step_pw<<<128, 256, 0, stream>>>(Gearly, E, c2, h3, c3, 64);
  decide(2, h3, 2, cls, cls, cls);

  // step 3: 64-class tiled GEMM -> 512-class h4,c4
  gemm64<<<32, 256, 0, stream>>>(h3, w_hh, Gearly);
  step_pw<<<1024, 256, 0, stream>>>(Gearly, E, c3, h4, c4, 512);
  decide(3, h4, 2, cls, nullptr, nullptr);

  // step 4: 512-class GEMM, expand to full rows (+ emit AcatA for step 5)
  gemm64<<<256, 256, 0, stream>>>(h4, w_hh, Gearly);
  expand_pw<<<(Bsz * Hsz) / 256, 256, 0, stream>>>(Gearly, E, c4, cls, act, hA,
                                                   cF, AcatA);
  decide(4, hA, 1, nullptr, nullptr, nullptr);

  // steps 5-7: split-bf16 MFMA GEMM + fused pointwise (A-cat ping-pong)
  ushort_t* ain = AcatA;
  ushort_t* aout = AcatB;
  for (int s = 5; s < 8; ++s) {
    gemm_bf16_lstm<<<512, 256, 0, stream>>>(ain, Wcat, Eperm, act, cF, hA, aout);
    decide(s, hA, 1, nullptr, nullptr, nullptr);
    ushort_t* t = ain; ain = aout; aout = t;
  }
}